// Round 3
// baseline (1923.042 us; speedup 1.0000x reference)
//
#include <hip/hip_runtime.h>
#include <math.h>

#define COMP(v, j) ((j)==0 ? (v).x : (j)==1 ? (v).y : (j)==2 ? (v).z : (v).w)

// ---------------- CSR build ----------------
__global__ void hist_k(const int* __restrict__ dst, int* __restrict__ cnt, int E) {
  int stride = gridDim.x * blockDim.x;
  for (int e = blockIdx.x * blockDim.x + threadIdx.x; e < E; e += stride)
    atomicAdd(&cnt[dst[e]], 1);
}

__global__ __launch_bounds__(1024) void scan_k(const int* __restrict__ cnt,
                                               int* __restrict__ rp, int N, int E) {
  __shared__ int buf[2048];
  int tid = threadIdx.x;
  int per = (N + 1023) >> 10;
  int s0 = min(N, tid * per), s1 = min(N, s0 + per);
  int sum = 0;
  for (int i = s0; i < s1; ++i) sum += cnt[i];
  buf[tid] = sum;
  __syncthreads();
  int pin = 0;
  for (int off = 1; off < 1024; off <<= 1) {
    int v = buf[pin * 1024 + tid];
    if (tid >= off) v += buf[pin * 1024 + tid - off];
    buf[(1 - pin) * 1024 + tid] = v;
    __syncthreads();
    pin = 1 - pin;
  }
  int run = (tid == 0) ? 0 : buf[pin * 1024 + tid - 1];
  for (int i = s0; i < s1; ++i) { rp[i] = run; run += cnt[i]; }
  if (tid == 0) rp[N] = E;
}

__global__ void scatter_k(const int* __restrict__ src, const int* __restrict__ dst,
                          const float* __restrict__ w, const int* __restrict__ rp,
                          int* __restrict__ cnt, int* __restrict__ ssrc,
                          float* __restrict__ sw, int E) {
  int stride = gridDim.x * blockDim.x;
  for (int e = blockIdx.x * blockDim.x + threadIdx.x; e < E; e += stride) {
    int d = dst[e];
    int off = atomicAdd(&cnt[d], 1);
    int p = rp[d] + off;
    ssrc[p] = src[e];
    sw[p]   = w[e];
  }
}

// ---------------- SpMM (pull, CSR by dst) + initial-residual mix ----------------
// out[i,:] = 0.9 * sum_e w_e * h[src_e,:]  +  0.1 * x0[i,:]
__global__ __launch_bounds__(256) void spmm_k(const int* __restrict__ rp,
    const int* __restrict__ ssrc, const float* __restrict__ sw,
    const float* __restrict__ h, const float* __restrict__ x0,
    float* __restrict__ out, int N) {
  int gw = (blockIdx.x * blockDim.x + threadIdx.x) >> 6;
  int lane = threadIdx.x & 63;
  if (gw >= N) return;
  int b = __builtin_amdgcn_readfirstlane(rp[gw]);
  int e = __builtin_amdgcn_readfirstlane(rp[gw + 1]);
  float ax = 0.f, ay = 0.f;
  int j = b;
  for (; j + 4 <= e; j += 4) {
    // wave-uniform edge metadata -> SGPRs
    int   s0_ = __builtin_amdgcn_readfirstlane(ssrc[j]);
    int   s1_ = __builtin_amdgcn_readfirstlane(ssrc[j+1]);
    int   s2_ = __builtin_amdgcn_readfirstlane(ssrc[j+2]);
    int   s3_ = __builtin_amdgcn_readfirstlane(ssrc[j+3]);
    float w0 = sw[j], w1 = sw[j+1], w2 = sw[j+2], w3 = sw[j+3];
    float2 v0 = ((const float2*)h)[(size_t)s0_ * 64 + lane];
    float2 v1 = ((const float2*)h)[(size_t)s1_ * 64 + lane];
    float2 v2 = ((const float2*)h)[(size_t)s2_ * 64 + lane];
    float2 v3 = ((const float2*)h)[(size_t)s3_ * 64 + lane];
    ax = fmaf(w0, v0.x, ax); ay = fmaf(w0, v0.y, ay);
    ax = fmaf(w1, v1.x, ax); ay = fmaf(w1, v1.y, ay);
    ax = fmaf(w2, v2.x, ax); ay = fmaf(w2, v2.y, ay);
    ax = fmaf(w3, v3.x, ax); ay = fmaf(w3, v3.y, ay);
  }
  for (; j < e; ++j) {
    int s = __builtin_amdgcn_readfirstlane(ssrc[j]);
    float w = sw[j];
    float2 v = ((const float2*)h)[(size_t)s * 64 + lane];
    ax = fmaf(w, v.x, ax); ay = fmaf(w, v.y, ay);
  }
  float2 xv = ((const float2*)x0)[(size_t)gw * 64 + lane];
  float2 o;
  o.x = 0.9f * ax + 0.1f * xv.x;
  o.y = 0.9f * ay + 0.1f * xv.y;
  ((float2*)out)[(size_t)gw * 64 + lane] = o;
}

// ---------------- dense 128x128 row-GEMM: res = cin*in + cw*(in@W) (+bias), opt relu ----------------
template<int RELU, int HAS_BIAS, int COPY2>
__global__ __launch_bounds__(256) void gemm128_k(const float* __restrict__ in,
    const float* __restrict__ W, const float* __restrict__ bias,
    float* __restrict__ out, float* __restrict__ out2,
    float cin, float cw, int N) {
  __shared__ float Wl[128 * 128];
  __shared__ float rowl[4][4 * 128];
  int tid = threadIdx.x;
  for (int i = tid; i < 128 * 128 / 4; i += 256)
    ((float4*)Wl)[i] = ((const float4*)W)[i];
  int wave = tid >> 6, lane = tid & 63;
  int rbase = (blockIdx.x * 4 + wave) * 4;
  float2 vin[4];
  #pragma unroll
  for (int r = 0; r < 4; ++r) {
    int row = rbase + r;
    float2 v = make_float2(0.f, 0.f);
    if (row < N) v = ((const float2*)in)[(size_t)row * 64 + lane];
    vin[r] = v;
    ((float2*)&rowl[wave][r * 128])[lane] = v;
  }
  __syncthreads();
  float2 bv = make_float2(0.f, 0.f);
  if (HAS_BIAS) bv = ((const float2*)bias)[lane];
  float2 acc0 = {0,0}, acc1 = {0,0}, acc2 = {0,0}, acc3 = {0,0};
  #pragma unroll 8
  for (int k4 = 0; k4 < 32; ++k4) {
    float4 a0 = *(const float4*)&rowl[wave][0 * 128 + k4 * 4];
    float4 a1 = *(const float4*)&rowl[wave][1 * 128 + k4 * 4];
    float4 a2 = *(const float4*)&rowl[wave][2 * 128 + k4 * 4];
    float4 a3 = *(const float4*)&rowl[wave][3 * 128 + k4 * 4];
    #pragma unroll
    for (int j = 0; j < 4; ++j) {
      float2 wv = *(const float2*)&Wl[(k4 * 4 + j) * 128 + 2 * lane];
      float e0 = COMP(a0, j), e1 = COMP(a1, j), e2 = COMP(a2, j), e3 = COMP(a3, j);
      acc0.x = fmaf(e0, wv.x, acc0.x); acc0.y = fmaf(e0, wv.y, acc0.y);
      acc1.x = fmaf(e1, wv.x, acc1.x); acc1.y = fmaf(e1, wv.y, acc1.y);
      acc2.x = fmaf(e2, wv.x, acc2.x); acc2.y = fmaf(e2, wv.y, acc2.y);
      acc3.x = fmaf(e3, wv.x, acc3.x); acc3.y = fmaf(e3, wv.y, acc3.y);
    }
  }
  float2 accs[4] = {acc0, acc1, acc2, acc3};
  #pragma unroll
  for (int r = 0; r < 4; ++r) {
    int row = rbase + r;
    if (row >= N) continue;
    float2 res;
    res.x = cin * vin[r].x + cw * accs[r].x + bv.x;
    res.y = cin * vin[r].y + cw * accs[r].y + bv.y;
    if (RELU) { res.x = fmaxf(res.x, 0.f); res.y = fmaxf(res.y, 0.f); }
    ((float2*)out)[(size_t)row * 64 + lane] = res;
    if (COPY2) ((float2*)out2)[(size_t)row * 64 + lane] = res;
  }
}

// ---------------- final: logits = in@W1 + b1, then log_softmax over 128 ----------------
__global__ __launch_bounds__(256) void final_k(const float* __restrict__ in,
    const float* __restrict__ W, const float* __restrict__ bias,
    float* __restrict__ out, int N) {
  __shared__ float Wl[128 * 128];
  __shared__ float rowl[4][4 * 128];
  int tid = threadIdx.x;
  for (int i = tid; i < 128 * 128 / 4; i += 256)
    ((float4*)Wl)[i] = ((const float4*)W)[i];
  int wave = tid >> 6, lane = tid & 63;
  int rbase = (blockIdx.x * 4 + wave) * 4;
  #pragma unroll
  for (int r = 0; r < 4; ++r) {
    int row = rbase + r;
    float2 v = make_float2(0.f, 0.f);
    if (row < N) v = ((const float2*)in)[(size_t)row * 64 + lane];
    ((float2*)&rowl[wave][r * 128])[lane] = v;
  }
  __syncthreads();
  float2 bv = ((const float2*)bias)[lane];
  float2 acc0 = {0,0}, acc1 = {0,0}, acc2 = {0,0}, acc3 = {0,0};
  #pragma unroll 8
  for (int k4 = 0; k4 < 32; ++k4) {
    float4 a0 = *(const float4*)&rowl[wave][0 * 128 + k4 * 4];
    float4 a1 = *(const float4*)&rowl[wave][1 * 128 + k4 * 4];
    float4 a2 = *(const float4*)&rowl[wave][2 * 128 + k4 * 4];
    float4 a3 = *(const float4*)&rowl[wave][3 * 128 + k4 * 4];
    #pragma unroll
    for (int j = 0; j < 4; ++j) {
      float2 wv = *(const float2*)&Wl[(k4 * 4 + j) * 128 + 2 * lane];
      float e0 = COMP(a0, j), e1 = COMP(a1, j), e2 = COMP(a2, j), e3 = COMP(a3, j);
      acc0.x = fmaf(e0, wv.x, acc0.x); acc0.y = fmaf(e0, wv.y, acc0.y);
      acc1.x = fmaf(e1, wv.x, acc1.x); acc1.y = fmaf(e1, wv.y, acc1.y);
      acc2.x = fmaf(e2, wv.x, acc2.x); acc2.y = fmaf(e2, wv.y, acc2.y);
      acc3.x = fmaf(e3, wv.x, acc3.x); acc3.y = fmaf(e3, wv.y, acc3.y);
    }
  }
  float2 accs[4] = {acc0, acc1, acc2, acc3};
  #pragma unroll
  for (int r = 0; r < 4; ++r) {
    int row = rbase + r;
    float2 y;
    y.x = accs[r].x + bv.x;
    y.y = accs[r].y + bv.y;
    float m = fmaxf(y.x, y.y);
    #pragma unroll
    for (int off = 32; off; off >>= 1) m = fmaxf(m, __shfl_xor(m, off));
    float s = expf(y.x - m) + expf(y.y - m);
    #pragma unroll
    for (int off = 32; off; off >>= 1) s += __shfl_xor(s, off);
    float lg = m + logf(s);
    if (row < N) {
      float2 res; res.x = y.x - lg; res.y = y.y - lg;
      ((float2*)out)[(size_t)row * 64 + lane] = res;
    }
  }
}

extern "C" void kernel_launch(void* const* d_in, const int* in_sizes, int n_in,
                              void* d_out, int out_size, void* d_ws, size_t ws_size,
                              hipStream_t stream) {
  const float* x     = (const float*)d_in[0];
  const int*   esrc  = (const int*)d_in[1];
  const int*   edst  = (const int*)d_in[2];
  const float* ew    = (const float*)d_in[3];
  const float* W0    = (const float*)d_in[4];
  const float* b0    = (const float*)d_in[5];
  const float* W1    = (const float*)d_in[6];
  const float* b1    = (const float*)d_in[7];
  const float* convW = (const float*)d_in[8];
  int N = in_sizes[0] / 128;
  int E = in_sizes[1];
  float* outp = (float*)d_out;

  char* ws = (char*)d_ws;
  size_t off = 0;
  auto alloc = [&](size_t bytes) {
    void* p = ws + off;
    off += (bytes + 255) & ~(size_t)255;
    return p;
  };
  float* x0   = (float*)alloc((size_t)N * 128 * 4);
  float* bufA = (float*)alloc((size_t)N * 128 * 4);
  float* bufB = (float*)alloc((size_t)N * 128 * 4);
  int*   rp   = (int*)alloc((size_t)(N + 1) * 4);
  int*   cnt  = (int*)alloc((size_t)N * 4);
  int*   ssrc = (int*)alloc((size_t)E * 4);
  float* swt  = (float*)alloc((size_t)E * 4);

  // ---- CSR build (every call; atomics only on 4B counters) ----
  hipMemsetAsync(cnt, 0, (size_t)N * 4, stream);
  hist_k<<<2048, 256, 0, stream>>>(edst, cnt, E);
  scan_k<<<1, 1024, 0, stream>>>(cnt, rp, N, E);
  hipMemsetAsync(cnt, 0, (size_t)N * 4, stream);
  scatter_k<<<2048, 256, 0, stream>>>(esrc, edst, ew, rp, cnt, ssrc, swt, E);

  int gemmBlocks = (N + 15) / 16;
  int spmmBlocks = (N + 3) / 4;

  // ---- input projection: h = relu(x@W0 + b0); x0 = h ----
  gemm128_k<1, 1, 1><<<gemmBlocks, 256, 0, stream>>>(x, W0, b0, bufA, x0, 0.f, 1.f, N);

  // ---- 4 GCNII layers ----
  for (int l = 0; l < 4; ++l) {
    float beta = logf(0.5f / (float)(l + 1) + 1.f);
    spmm_k<<<spmmBlocks, 256, 0, stream>>>(rp, ssrc, swt, bufA, x0, bufB, N);
    gemm128_k<1, 0, 0><<<gemmBlocks, 256, 0, stream>>>(
        bufB, convW + (size_t)l * 128 * 128, nullptr, bufA, nullptr,
        1.f - beta, beta, N);
  }

  // ---- final: logits + log_softmax ----
  final_k<<<gemmBlocks, 256, 0, stream>>>(bufA, W1, b1, outp, N);
}

// Round 4
// 1162.771 us; speedup vs baseline: 1.6538x; 1.6538x over previous
//
#include <hip/hip_runtime.h>
#include <math.h>

// ---------------- CSR build ----------------
__global__ void hist_k(const int* __restrict__ dst, int* __restrict__ cnt, int E) {
  int stride = gridDim.x * blockDim.x;
  for (int e = blockIdx.x * blockDim.x + threadIdx.x; e < E; e += stride)
    atomicAdd(&cnt[dst[e]], 1);
}

__global__ __launch_bounds__(1024) void scan_k(const int* __restrict__ cnt,
                                               int* __restrict__ rp, int N, int E) {
  __shared__ int buf[2048];
  int tid = threadIdx.x;
  int per = (N + 1023) >> 10;
  int s0 = min(N, tid * per), s1 = min(N, s0 + per);
  int sum = 0;
  for (int i = s0; i < s1; ++i) sum += cnt[i];
  buf[tid] = sum;
  __syncthreads();
  int pin = 0;
  for (int off = 1; off < 1024; off <<= 1) {
    int v = buf[pin * 1024 + tid];
    if (tid >= off) v += buf[pin * 1024 + tid - off];
    buf[(1 - pin) * 1024 + tid] = v;
    __syncthreads();
    pin = 1 - pin;
  }
  int run = (tid == 0) ? 0 : buf[pin * 1024 + tid - 1];
  for (int i = s0; i < s1; ++i) { rp[i] = run; run += cnt[i]; }
  if (tid == 0) rp[N] = E;
}

__global__ void scatter_k(const int* __restrict__ src, const int* __restrict__ dst,
                          const float* __restrict__ w, const int* __restrict__ rp,
                          int* __restrict__ cnt, int* __restrict__ ssrc,
                          float* __restrict__ sw, int E) {
  int stride = gridDim.x * blockDim.x;
  for (int e = blockIdx.x * blockDim.x + threadIdx.x; e < E; e += stride) {
    int d = dst[e];
    int off = atomicAdd(&cnt[d], 1);
    int p = rp[d] + off;
    ssrc[p] = src[e];
    sw[p]   = w[e];
  }
}

// ---------------- SpMM (pull, CSR by dst) + initial-residual mix ----------------
// out[i,:] = 0.9 * sum_e w_e * h[src_e,:]  +  0.1 * x0[i,:]
// One node per wave; lanes split into two 32-lane halves, each half gathers a
// full 128-float row as float4 for one edge; halves combined by shfl at end.
__global__ __launch_bounds__(256) void spmm_k(const int* __restrict__ rp,
    const int* __restrict__ ssrc, const float* __restrict__ sw,
    const float* __restrict__ h, const float* __restrict__ x0,
    float* __restrict__ out, int N) {
  int gw = (blockIdx.x * blockDim.x + threadIdx.x) >> 6;
  int lane = threadIdx.x & 63;
  if (gw >= N) return;
  int half = lane >> 5, l32 = lane & 31;
  int b = __builtin_amdgcn_readfirstlane(rp[gw]);
  int e = __builtin_amdgcn_readfirstlane(rp[gw + 1]);
  float4 acc = make_float4(0.f, 0.f, 0.f, 0.f);
  int j = b + half;
  for (; j + 2 < e; j += 4) {  // this half: edges j and j+2 (4 edges/wave/iter)
    int   s0 = ssrc[j];
    int   s1 = ssrc[j + 2];
    float w0 = sw[j];
    float w1 = sw[j + 2];
    float4 v0 = ((const float4*)h)[(size_t)s0 * 32 + l32];
    float4 v1 = ((const float4*)h)[(size_t)s1 * 32 + l32];
    acc.x = fmaf(w0, v0.x, acc.x); acc.y = fmaf(w0, v0.y, acc.y);
    acc.z = fmaf(w0, v0.z, acc.z); acc.w = fmaf(w0, v0.w, acc.w);
    acc.x = fmaf(w1, v1.x, acc.x); acc.y = fmaf(w1, v1.y, acc.y);
    acc.z = fmaf(w1, v1.z, acc.z); acc.w = fmaf(w1, v1.w, acc.w);
  }
  for (; j < e; j += 2) {
    int s = ssrc[j];
    float w = sw[j];
    float4 v = ((const float4*)h)[(size_t)s * 32 + l32];
    acc.x = fmaf(w, v.x, acc.x); acc.y = fmaf(w, v.y, acc.y);
    acc.z = fmaf(w, v.z, acc.z); acc.w = fmaf(w, v.w, acc.w);
  }
  // combine the two halves (lane ^ 32 holds the other parity's partial sum)
  acc.x += __shfl_xor(acc.x, 32);
  acc.y += __shfl_xor(acc.y, 32);
  acc.z += __shfl_xor(acc.z, 32);
  acc.w += __shfl_xor(acc.w, 32);
  if (half == 0) {
    float4 xv = ((const float4*)x0)[(size_t)gw * 32 + l32];
    float4 o;
    o.x = 0.9f * acc.x + 0.1f * xv.x;
    o.y = 0.9f * acc.y + 0.1f * xv.y;
    o.z = 0.9f * acc.z + 0.1f * xv.z;
    o.w = 0.9f * acc.w + 0.1f * xv.w;
    ((float4*)out)[(size_t)gw * 32 + l32] = o;
  }
}

// ---------------- tiled dense GEMM: 128x128 tile, BK=32, 8x8 per thread ----------------
// MODE 0 (proj):  out = relu(in@W + bias); out2 = out        (cin unused)
// MODE 1 (conv):  out = relu(cin*in + cw*(in@W))             (re-reads in at epilogue)
// MODE 2 (final): out = log_softmax(in@W + bias, axis=-1)
template<int MODE>
__global__ __launch_bounds__(256, 4) void gemm_tiled(const float* __restrict__ in,
    const float* __restrict__ W, const float* __restrict__ bias,
    float* __restrict__ out, float* __restrict__ out2,
    float cin, float cw, int N) {
  __shared__ float As[32][132];   // k-major, transposed A tile
  __shared__ float Ws[32][132];   // k-major W tile
  int tid = threadIdx.x;
  int tx = tid & 15;              // col group (lane bits 0-3)
  int ty = tid >> 4;              // row group
  int rbase = blockIdx.x * 128;

  float4 acc[8][2];
  #pragma unroll
  for (int i = 0; i < 8; ++i) {
    acc[i][0] = make_float4(0.f, 0.f, 0.f, 0.f);
    acc[i][1] = make_float4(0.f, 0.f, 0.f, 0.f);
  }

  for (int kt = 0; kt < 4; ++kt) {
    // stage A (transpose): 128 rows x 32 k = 1024 float4 chunks, 4/thread
    #pragma unroll
    for (int i = 0; i < 4; ++i) {
      int f = tid + 256 * i;
      int r = f >> 3, c = f & 7;
      int grow = rbase + r;
      float4 v = make_float4(0.f, 0.f, 0.f, 0.f);
      if (grow < N) v = *(const float4*)&in[(size_t)grow * 128 + kt * 32 + c * 4];
      As[c * 4 + 0][r] = v.x;
      As[c * 4 + 1][r] = v.y;
      As[c * 4 + 2][r] = v.z;
      As[c * 4 + 3][r] = v.w;
    }
    // stage W: 32 k x 128 n, direct copy
    #pragma unroll
    for (int i = 0; i < 4; ++i) {
      int f = tid + 256 * i;
      int k = f >> 5, n4 = f & 31;
      *(float4*)&Ws[k][n4 * 4] = *(const float4*)&W[(size_t)(kt * 32 + k) * 128 + n4 * 4];
    }
    __syncthreads();
    #pragma unroll 8
    for (int k = 0; k < 32; ++k) {
      float4 al = *(const float4*)&As[k][4 * ty];
      float4 ah = *(const float4*)&As[k][64 + 4 * ty];
      float4 wl = *(const float4*)&Ws[k][4 * tx];
      float4 wh = *(const float4*)&Ws[k][64 + 4 * tx];
      float a_[8] = {al.x, al.y, al.z, al.w, ah.x, ah.y, ah.z, ah.w};
      #pragma unroll
      for (int i = 0; i < 8; ++i) {
        acc[i][0].x = fmaf(a_[i], wl.x, acc[i][0].x);
        acc[i][0].y = fmaf(a_[i], wl.y, acc[i][0].y);
        acc[i][0].z = fmaf(a_[i], wl.z, acc[i][0].z);
        acc[i][0].w = fmaf(a_[i], wl.w, acc[i][0].w);
        acc[i][1].x = fmaf(a_[i], wh.x, acc[i][1].x);
        acc[i][1].y = fmaf(a_[i], wh.y, acc[i][1].y);
        acc[i][1].z = fmaf(a_[i], wh.z, acc[i][1].z);
        acc[i][1].w = fmaf(a_[i], wh.w, acc[i][1].w);
      }
    }
    __syncthreads();
  }

  // epilogue
  float4 bl = make_float4(0.f, 0.f, 0.f, 0.f), bh = bl;
  if (MODE != 1) {
    bl = *(const float4*)&bias[4 * tx];
    bh = *(const float4*)&bias[64 + 4 * tx];
  }
  #pragma unroll
  for (int i = 0; i < 8; ++i) {
    int r = rbase + ((i < 4) ? (4 * ty + i) : (64 + 4 * ty + (i - 4)));
    bool valid = (r < N);
    float4 y0 = acc[i][0], y1 = acc[i][1];
    if (MODE == 1) {
      float4 i0 = make_float4(0.f,0.f,0.f,0.f), i1 = i0;
      if (valid) {
        i0 = *(const float4*)&in[(size_t)r * 128 + 4 * tx];
        i1 = *(const float4*)&in[(size_t)r * 128 + 64 + 4 * tx];
      }
      y0.x = fmaxf(cin * i0.x + cw * y0.x, 0.f);
      y0.y = fmaxf(cin * i0.y + cw * y0.y, 0.f);
      y0.z = fmaxf(cin * i0.z + cw * y0.z, 0.f);
      y0.w = fmaxf(cin * i0.w + cw * y0.w, 0.f);
      y1.x = fmaxf(cin * i1.x + cw * y1.x, 0.f);
      y1.y = fmaxf(cin * i1.y + cw * y1.y, 0.f);
      y1.z = fmaxf(cin * i1.z + cw * y1.z, 0.f);
      y1.w = fmaxf(cin * i1.w + cw * y1.w, 0.f);
    } else {
      y0.x += bl.x; y0.y += bl.y; y0.z += bl.z; y0.w += bl.w;
      y1.x += bh.x; y1.y += bh.y; y1.z += bh.z; y1.w += bh.w;
      if (MODE == 0) {
        y0.x = fmaxf(y0.x, 0.f); y0.y = fmaxf(y0.y, 0.f);
        y0.z = fmaxf(y0.z, 0.f); y0.w = fmaxf(y0.w, 0.f);
        y1.x = fmaxf(y1.x, 0.f); y1.y = fmaxf(y1.y, 0.f);
        y1.z = fmaxf(y1.z, 0.f); y1.w = fmaxf(y1.w, 0.f);
      }
    }
    if (MODE == 2) {
      // log-softmax over the 128 cols of row r (spread across the 16 tx lanes)
      float m = fmaxf(fmaxf(fmaxf(y0.x, y0.y), fmaxf(y0.z, y0.w)),
                      fmaxf(fmaxf(y1.x, y1.y), fmaxf(y1.z, y1.w)));
      #pragma unroll
      for (int off = 1; off <= 8; off <<= 1) m = fmaxf(m, __shfl_xor(m, off));
      float s = expf(y0.x - m) + expf(y0.y - m) + expf(y0.z - m) + expf(y0.w - m)
              + expf(y1.x - m) + expf(y1.y - m) + expf(y1.z - m) + expf(y1.w - m);
      #pragma unroll
      for (int off = 1; off <= 8; off <<= 1) s += __shfl_xor(s, off);
      float lg = m + logf(s);
      y0.x -= lg; y0.y -= lg; y0.z -= lg; y0.w -= lg;
      y1.x -= lg; y1.y -= lg; y1.z -= lg; y1.w -= lg;
    }
    if (valid) {
      *(float4*)&out[(size_t)r * 128 + 4 * tx] = y0;
      *(float4*)&out[(size_t)r * 128 + 64 + 4 * tx] = y1;
      if (MODE == 0) {
        *(float4*)&out2[(size_t)r * 128 + 4 * tx] = y0;
        *(float4*)&out2[(size_t)r * 128 + 64 + 4 * tx] = y1;
      }
    }
  }
}

extern "C" void kernel_launch(void* const* d_in, const int* in_sizes, int n_in,
                              void* d_out, int out_size, void* d_ws, size_t ws_size,
                              hipStream_t stream) {
  const float* x     = (const float*)d_in[0];
  const int*   esrc  = (const int*)d_in[1];
  const int*   edst  = (const int*)d_in[2];
  const float* ew    = (const float*)d_in[3];
  const float* W0    = (const float*)d_in[4];
  const float* b0    = (const float*)d_in[5];
  const float* W1    = (const float*)d_in[6];
  const float* b1    = (const float*)d_in[7];
  const float* convW = (const float*)d_in[8];
  int N = in_sizes[0] / 128;
  int E = in_sizes[1];
  float* outp = (float*)d_out;

  char* ws = (char*)d_ws;
  size_t off = 0;
  auto alloc = [&](size_t bytes) {
    void* p = ws + off;
    off += (bytes + 255) & ~(size_t)255;
    return p;
  };
  float* x0   = (float*)alloc((size_t)N * 128 * 4);
  float* bufA = (float*)alloc((size_t)N * 128 * 4);
  float* bufB = (float*)alloc((size_t)N * 128 * 4);
  int*   rp   = (int*)alloc((size_t)(N + 1) * 4);
  int*   cnt  = (int*)alloc((size_t)N * 4);
  int*   ssrc = (int*)alloc((size_t)E * 4);
  float* swt  = (float*)alloc((size_t)E * 4);

  // ---- CSR build (every call; atomics only on 4B counters) ----
  hipMemsetAsync(cnt, 0, (size_t)N * 4, stream);
  hist_k<<<2048, 256, 0, stream>>>(edst, cnt, E);
  scan_k<<<1, 1024, 0, stream>>>(cnt, rp, N, E);
  hipMemsetAsync(cnt, 0, (size_t)N * 4, stream);
  scatter_k<<<2048, 256, 0, stream>>>(esrc, edst, ew, rp, cnt, ssrc, swt, E);

  int gemmBlocks = (N + 127) / 128;
  int spmmBlocks = (N + 3) / 4;

  // ---- input projection: h = relu(x@W0 + b0); x0 = h ----
  gemm_tiled<0><<<gemmBlocks, 256, 0, stream>>>(x, W0, b0, bufA, x0, 0.f, 1.f, N);

  // ---- 4 GCNII layers ----
  for (int l = 0; l < 4; ++l) {
    float beta = logf(0.5f / (float)(l + 1) + 1.f);
    spmm_k<<<spmmBlocks, 256, 0, stream>>>(rp, ssrc, swt, bufA, x0, bufB, N);
    gemm_tiled<1><<<gemmBlocks, 256, 0, stream>>>(
        bufB, convW + (size_t)l * 128 * 128, nullptr, bufA, nullptr,
        1.f - beta, beta, N);
  }

  // ---- final: logits + log_softmax ----
  gemm_tiled<2><<<gemmBlocks, 256, 0, stream>>>(bufA, W1, b1, outp, nullptr, 0.f, 1.f, N);
}

// Round 5
// 808.585 us; speedup vs baseline: 2.3783x; 1.4380x over previous
//
#include <hip/hip_runtime.h>
#include <math.h>

typedef unsigned int uint;

__device__ inline uint packbf2(float a, float b) {
  uint ua = __float_as_uint(a), ub = __float_as_uint(b);
  ua = (ua + 0x7fffu + ((ua >> 16) & 1u)) >> 16;
  ub = (ub + 0x7fffu + ((ub >> 16) & 1u)) & 0xffff0000u;
  return ua | ub;
}
__device__ inline float bflo(uint u) { return __uint_as_float(u << 16); }
__device__ inline float bfhi(uint u) { return __uint_as_float(u & 0xffff0000u); }

// ---------------- CSR build ----------------
__global__ void hist_k(const int* __restrict__ dst, int* __restrict__ cnt, int E) {
  int stride = gridDim.x * blockDim.x;
  for (int e = blockIdx.x * blockDim.x + threadIdx.x; e < E; e += stride)
    atomicAdd(&cnt[dst[e]], 1);
}

// hierarchical scan: A = per-block reduce (1024 counts/block), B = scan block sums,
// C = per-block exclusive scan + writeback
__global__ __launch_bounds__(256) void scanA_k(const int* __restrict__ cnt,
                                               int* __restrict__ bsum, int N) {
  __shared__ int red[256];
  int tid = threadIdx.x;
  int i0 = blockIdx.x * 1024 + tid * 4;
  int s = 0;
  #pragma unroll
  for (int k = 0; k < 4; ++k) { int i = i0 + k; if (i < N) s += cnt[i]; }
  red[tid] = s;
  __syncthreads();
  for (int off = 128; off; off >>= 1) {
    if (tid < off) red[tid] += red[tid + off];
    __syncthreads();
  }
  if (tid == 0) bsum[blockIdx.x] = red[0];
}

__global__ __launch_bounds__(128) void scanB_k(const int* __restrict__ bsum,
                                               int* __restrict__ bbase, int nb) {
  __shared__ int buf[2][128];
  int tid = threadIdx.x;
  buf[0][tid] = (tid < nb) ? bsum[tid] : 0;
  __syncthreads();
  int pin = 0;
  for (int off = 1; off < 128; off <<= 1) {
    int x = buf[pin][tid];
    if (tid >= off) x += buf[pin][tid - off];
    buf[1 - pin][tid] = x;
    __syncthreads();
    pin = 1 - pin;
  }
  if (tid < nb) bbase[tid] = (tid == 0) ? 0 : buf[pin][tid - 1];
}

__global__ __launch_bounds__(256) void scanC_k(const int* __restrict__ cnt,
    const int* __restrict__ bbase, int* __restrict__ rp, int N, int E) {
  __shared__ int buf[2][256];
  int tid = threadIdx.x;
  int i0 = blockIdx.x * 1024 + tid * 4;
  int c[4]; int s = 0;
  #pragma unroll
  for (int k = 0; k < 4; ++k) { int i = i0 + k; c[k] = (i < N) ? cnt[i] : 0; s += c[k]; }
  buf[0][tid] = s;
  __syncthreads();
  int pin = 0;
  for (int off = 1; off < 256; off <<= 1) {
    int x = buf[pin][tid];
    if (tid >= off) x += buf[pin][tid - off];
    buf[1 - pin][tid] = x;
    __syncthreads();
    pin = 1 - pin;
  }
  int run = bbase[blockIdx.x] + buf[pin][tid] - s;  // exclusive prefix
  #pragma unroll
  for (int k = 0; k < 4; ++k) {
    int i = i0 + k;
    if (i < N) { rp[i] = run; run += c[k]; }
  }
  if (blockIdx.x == 0 && tid == 0) rp[N] = E;
}

__global__ void scatter_k(const int* __restrict__ src, const int* __restrict__ dst,
                          const float* __restrict__ w, const int* __restrict__ rp,
                          int* __restrict__ cnt, int2* __restrict__ epk, int E) {
  int stride = gridDim.x * blockDim.x;
  for (int e = blockIdx.x * blockDim.x + threadIdx.x; e < E; e += stride) {
    int d = dst[e];
    int off = atomicAdd(&cnt[d], 1);
    epk[rp[d] + off] = make_int2(src[e], __float_as_int(w[e]));
  }
}

// ---------------- SpMM (pull, CSR by dst, bf16 gather) + initial-residual mix ----------------
// out[i,:] = 0.9 * sum_e w_e * h[src_e,:]  +  0.1 * x0[i,:]
// One node per wave; two 32-lane halves each process alternating edges,
// gathering a full 128-col bf16 row as uint2 (4 bf16) per lane.
__global__ __launch_bounds__(256) void spmm_k(const int* __restrict__ rp,
    const int2* __restrict__ epk, const uint* __restrict__ hbf,
    const uint* __restrict__ x0bf, float* __restrict__ out, int N) {
  int gw = (blockIdx.x * blockDim.x + threadIdx.x) >> 6;
  int lane = threadIdx.x & 63;
  if (gw >= N) return;
  int half = lane >> 5, l32 = lane & 31;
  int b = __builtin_amdgcn_readfirstlane(rp[gw]);
  int e = __builtin_amdgcn_readfirstlane(rp[gw + 1]);
  float4 acc = make_float4(0.f, 0.f, 0.f, 0.f);
  int j = b + half;
  for (; j + 2 < e; j += 4) {   // this half: edges j, j+2 (4 edges/wave in flight)
    int2 e0 = epk[j], e1 = epk[j + 2];
    float w0 = __int_as_float(e0.y), w1 = __int_as_float(e1.y);
    uint2 h0 = ((const uint2*)hbf)[(size_t)e0.x * 32 + l32];
    uint2 h1 = ((const uint2*)hbf)[(size_t)e1.x * 32 + l32];
    acc.x = fmaf(w0, bflo(h0.x), acc.x); acc.y = fmaf(w0, bfhi(h0.x), acc.y);
    acc.z = fmaf(w0, bflo(h0.y), acc.z); acc.w = fmaf(w0, bfhi(h0.y), acc.w);
    acc.x = fmaf(w1, bflo(h1.x), acc.x); acc.y = fmaf(w1, bfhi(h1.x), acc.y);
    acc.z = fmaf(w1, bflo(h1.y), acc.z); acc.w = fmaf(w1, bfhi(h1.y), acc.w);
  }
  for (; j < e; j += 2) {
    int2 e0 = epk[j];
    float w0 = __int_as_float(e0.y);
    uint2 h0 = ((const uint2*)hbf)[(size_t)e0.x * 32 + l32];
    acc.x = fmaf(w0, bflo(h0.x), acc.x); acc.y = fmaf(w0, bfhi(h0.x), acc.y);
    acc.z = fmaf(w0, bflo(h0.y), acc.z); acc.w = fmaf(w0, bfhi(h0.y), acc.w);
  }
  acc.x += __shfl_xor(acc.x, 32);
  acc.y += __shfl_xor(acc.y, 32);
  acc.z += __shfl_xor(acc.z, 32);
  acc.w += __shfl_xor(acc.w, 32);
  if (half == 0) {
    uint2 xv = ((const uint2*)x0bf)[(size_t)gw * 32 + l32];
    float4 o;
    o.x = 0.9f * acc.x + 0.1f * bflo(xv.x);
    o.y = 0.9f * acc.y + 0.1f * bfhi(xv.x);
    o.z = 0.9f * acc.z + 0.1f * bflo(xv.y);
    o.w = 0.9f * acc.w + 0.1f * bfhi(xv.y);
    ((float4*)out)[(size_t)gw * 32 + l32] = o;
  }
}

// ---------------- tiled dense GEMM: 128x128 tile, BK=32, 8x8 per thread ----------------
// MODE 0 (proj):  y = relu(in@W + bias); store bf16 to outbf (h) and outbf2 (x0)
// MODE 1 (conv):  y = relu(cin*in + cw*(in@W)); store f32 to outf and/or bf16 to outbf
// MODE 2 (final): y = log_softmax(in@W + bias); store f32 to outf
template<int MODE>
__global__ __launch_bounds__(256, 4) void gemm_tiled(const float* __restrict__ in,
    const float* __restrict__ W, const float* __restrict__ bias,
    float* __restrict__ outf, uint* __restrict__ outbf, uint* __restrict__ outbf2,
    float cin, float cw, int N) {
  __shared__ float As[32][132];   // k-major, transposed A tile (+pad)
  __shared__ float Ws[32][132];   // k-major W tile (+pad)
  int tid = threadIdx.x;
  int tx = tid & 15;              // col group
  int ty = tid >> 4;              // row group
  int rbase = blockIdx.x * 128;

  float4 acc[8][2];
  #pragma unroll
  for (int i = 0; i < 8; ++i) {
    acc[i][0] = make_float4(0.f, 0.f, 0.f, 0.f);
    acc[i][1] = make_float4(0.f, 0.f, 0.f, 0.f);
  }

  for (int kt = 0; kt < 4; ++kt) {
    #pragma unroll
    for (int i = 0; i < 4; ++i) {
      int f = tid + 256 * i;
      int r = f >> 3, c = f & 7;
      int grow = rbase + r;
      float4 v = make_float4(0.f, 0.f, 0.f, 0.f);
      if (grow < N) v = *(const float4*)&in[(size_t)grow * 128 + kt * 32 + c * 4];
      As[c * 4 + 0][r] = v.x;
      As[c * 4 + 1][r] = v.y;
      As[c * 4 + 2][r] = v.z;
      As[c * 4 + 3][r] = v.w;
    }
    #pragma unroll
    for (int i = 0; i < 4; ++i) {
      int f = tid + 256 * i;
      int k = f >> 5, n4 = f & 31;
      *(float4*)&Ws[k][n4 * 4] = *(const float4*)&W[(size_t)(kt * 32 + k) * 128 + n4 * 4];
    }
    __syncthreads();
    #pragma unroll 8
    for (int k = 0; k < 32; ++k) {
      float4 al = *(const float4*)&As[k][4 * ty];
      float4 ah = *(const float4*)&As[k][64 + 4 * ty];
      float4 wl = *(const float4*)&Ws[k][4 * tx];
      float4 wh = *(const float4*)&Ws[k][64 + 4 * tx];
      float a_[8] = {al.x, al.y, al.z, al.w, ah.x, ah.y, ah.z, ah.w};
      #pragma unroll
      for (int i = 0; i < 8; ++i) {
        acc[i][0].x = fmaf(a_[i], wl.x, acc[i][0].x);
        acc[i][0].y = fmaf(a_[i], wl.y, acc[i][0].y);
        acc[i][0].z = fmaf(a_[i], wl.z, acc[i][0].z);
        acc[i][0].w = fmaf(a_[i], wl.w, acc[i][0].w);
        acc[i][1].x = fmaf(a_[i], wh.x, acc[i][1].x);
        acc[i][1].y = fmaf(a_[i], wh.y, acc[i][1].y);
        acc[i][1].z = fmaf(a_[i], wh.z, acc[i][1].z);
        acc[i][1].w = fmaf(a_[i], wh.w, acc[i][1].w);
      }
    }
    __syncthreads();
  }

  float4 bl = make_float4(0.f, 0.f, 0.f, 0.f), bh = bl;
  if (MODE != 1) {
    bl = *(const float4*)&bias[4 * tx];
    bh = *(const float4*)&bias[64 + 4 * tx];
  }
  #pragma unroll
  for (int i = 0; i < 8; ++i) {
    int r = rbase + ((i < 4) ? (4 * ty + i) : (64 + 4 * ty + (i - 4)));
    bool valid = (r < N);
    float4 y0 = acc[i][0], y1 = acc[i][1];
    if (MODE == 1) {
      float4 i0 = make_float4(0.f,0.f,0.f,0.f), i1 = i0;
      if (valid) {
        i0 = *(const float4*)&in[(size_t)r * 128 + 4 * tx];
        i1 = *(const float4*)&in[(size_t)r * 128 + 64 + 4 * tx];
      }
      y0.x = fmaxf(cin * i0.x + cw * y0.x, 0.f);
      y0.y = fmaxf(cin * i0.y + cw * y0.y, 0.f);
      y0.z = fmaxf(cin * i0.z + cw * y0.z, 0.f);
      y0.w = fmaxf(cin * i0.w + cw * y0.w, 0.f);
      y1.x = fmaxf(cin * i1.x + cw * y1.x, 0.f);
      y1.y = fmaxf(cin * i1.y + cw * y1.y, 0.f);
      y1.z = fmaxf(cin * i1.z + cw * y1.z, 0.f);
      y1.w = fmaxf(cin * i1.w + cw * y1.w, 0.f);
    } else {
      y0.x += bl.x; y0.y += bl.y; y0.z += bl.z; y0.w += bl.w;
      y1.x += bh.x; y1.y += bh.y; y1.z += bh.z; y1.w += bh.w;
      if (MODE == 0) {
        y0.x = fmaxf(y0.x, 0.f); y0.y = fmaxf(y0.y, 0.f);
        y0.z = fmaxf(y0.z, 0.f); y0.w = fmaxf(y0.w, 0.f);
        y1.x = fmaxf(y1.x, 0.f); y1.y = fmaxf(y1.y, 0.f);
        y1.z = fmaxf(y1.z, 0.f); y1.w = fmaxf(y1.w, 0.f);
      }
    }
    if (MODE == 2) {
      float m = fmaxf(fmaxf(fmaxf(y0.x, y0.y), fmaxf(y0.z, y0.w)),
                      fmaxf(fmaxf(y1.x, y1.y), fmaxf(y1.z, y1.w)));
      #pragma unroll
      for (int off = 1; off <= 8; off <<= 1) m = fmaxf(m, __shfl_xor(m, off));
      float s = expf(y0.x - m) + expf(y0.y - m) + expf(y0.z - m) + expf(y0.w - m)
              + expf(y1.x - m) + expf(y1.y - m) + expf(y1.z - m) + expf(y1.w - m);
      #pragma unroll
      for (int off = 1; off <= 8; off <<= 1) s += __shfl_xor(s, off);
      float lg = m + logf(s);
      y0.x -= lg; y0.y -= lg; y0.z -= lg; y0.w -= lg;
      y1.x -= lg; y1.y -= lg; y1.z -= lg; y1.w -= lg;
    }
    if (valid) {
      if (MODE == 2 || (MODE == 1 && outf)) {
        *(float4*)&outf[(size_t)r * 128 + 4 * tx] = y0;
        *(float4*)&outf[(size_t)r * 128 + 64 + 4 * tx] = y1;
      }
      if (MODE != 2 && outbf) {
        uint2 u0 = make_uint2(packbf2(y0.x, y0.y), packbf2(y0.z, y0.w));
        uint2 u1 = make_uint2(packbf2(y1.x, y1.y), packbf2(y1.z, y1.w));
        ((uint2*)outbf)[(size_t)r * 32 + tx] = u0;
        ((uint2*)outbf)[(size_t)r * 32 + 16 + tx] = u1;
        if (MODE == 0) {
          ((uint2*)outbf2)[(size_t)r * 32 + tx] = u0;
          ((uint2*)outbf2)[(size_t)r * 32 + 16 + tx] = u1;
        }
      }
    }
  }
}

extern "C" void kernel_launch(void* const* d_in, const int* in_sizes, int n_in,
                              void* d_out, int out_size, void* d_ws, size_t ws_size,
                              hipStream_t stream) {
  const float* x     = (const float*)d_in[0];
  const int*   esrc  = (const int*)d_in[1];
  const int*   edst  = (const int*)d_in[2];
  const float* ew    = (const float*)d_in[3];
  const float* W0    = (const float*)d_in[4];
  const float* b0    = (const float*)d_in[5];
  const float* W1    = (const float*)d_in[6];
  const float* b1    = (const float*)d_in[7];
  const float* convW = (const float*)d_in[8];
  int N = in_sizes[0] / 128;
  int E = in_sizes[1];
  float* outp = (float*)d_out;

  char* ws = (char*)d_ws;
  size_t off = 0;
  auto alloc = [&](size_t bytes) {
    void* p = ws + off;
    off += (bytes + 255) & ~(size_t)255;
    return p;
  };
  uint*  hbf  = (uint*)alloc((size_t)N * 128 * 2);
  uint*  x0bf = (uint*)alloc((size_t)N * 128 * 2);
  float* bufA = (float*)alloc((size_t)N * 128 * 4);
  float* bufB = (float*)alloc((size_t)N * 128 * 4);
  int*   rp   = (int*)alloc((size_t)(N + 1) * 4);
  int*   cnt  = (int*)alloc((size_t)N * 4);
  int2*  epk  = (int2*)alloc((size_t)E * 8);
  int nbScan = (N + 1023) / 1024;
  int*   bsum  = (int*)alloc((size_t)nbScan * 4);
  int*   bbase = (int*)alloc((size_t)nbScan * 4);

  // ---- CSR build ----
  hipMemsetAsync(cnt, 0, (size_t)N * 4, stream);
  hist_k<<<2048, 256, 0, stream>>>(edst, cnt, E);
  scanA_k<<<nbScan, 256, 0, stream>>>(cnt, bsum, N);
  scanB_k<<<1, 128, 0, stream>>>(bsum, bbase, nbScan);
  scanC_k<<<nbScan, 256, 0, stream>>>(cnt, bbase, rp, N, E);
  hipMemsetAsync(cnt, 0, (size_t)N * 4, stream);
  scatter_k<<<2048, 256, 0, stream>>>(esrc, edst, ew, rp, cnt, epk, E);

  int gemmBlocks = (N + 127) / 128;
  int spmmBlocks = (N + 3) / 4;

  // ---- input projection: h = relu(x@W0 + b0) -> hbf, x0bf (bf16) ----
  gemm_tiled<0><<<gemmBlocks, 256, 0, stream>>>(x, W0, b0, nullptr, hbf, x0bf, 0.f, 1.f, N);

  // ---- 4 GCNII layers ----
  for (int l = 0; l < 4; ++l) {
    float beta = logf(0.5f / (float)(l + 1) + 1.f);
    spmm_k<<<spmmBlocks, 256, 0, stream>>>(rp, epk, hbf, x0bf, bufB, N);
    gemm_tiled<1><<<gemmBlocks, 256, 0, stream>>>(
        bufB, convW + (size_t)l * 128 * 128, nullptr,
        (l == 3) ? bufA : nullptr, (l == 3) ? nullptr : hbf, nullptr,
        1.f - beta, beta, N);
  }

  // ---- final: logits + log_softmax ----
  gemm_tiled<2><<<gemmBlocks, 256, 0, stream>>>(bufA, W1, b1, outp, nullptr, nullptr, 0.f, 1.f, N);
}